// Round 1
// baseline (324.659 us; speedup 1.0000x reference)
//
#include <hip/hip_runtime.h>

#define D 128
#define NBB 788   // bucket array stride (>= nbkt+1), nbkt = ceil(50000/64) = 782

typedef __attribute__((ext_vector_type(8))) short bf16x8;
typedef __attribute__((ext_vector_type(4))) float f32x4;

__device__ inline unsigned short f2bf(float f) {
  unsigned u = __builtin_bit_cast(unsigned, f);
  unsigned r = u + 0x7FFFu + ((u >> 16) & 1u);
  return (unsigned short)(r >> 16);
}
__device__ inline float bf2f(unsigned short b) {
  unsigned u = ((unsigned)b) << 16;
  return __builtin_bit_cast(float, u);
}

// ------- fused setup: conv (fp32->bf16) | bucket hist | weight prep -------
struct SetupArgs {
  // conv
  const float* xu; const float* xi;
  unsigned short* xbu; unsigned short* xbi;
  int n4u, n4i, nbConv;
  // bhist
  const int* ei[3]; int ne[3]; int nbh[3]; int nbHist;
  int* bh;
  // prep
  const float* Wl_rates; const float* Wr_rates; const float* bl_rates;
  const float* Wl_rev;   const float* Wr_rev;   const float* bl_rev;
  const float* Wl_fol;   const float* Wr_fol;   const float* bl_fol;
  unsigned short* Wb_user; unsigned short* Wb_item;
  float* b_user; float* b_item;
};

__global__ void __launch_bounds__(256) setup_kernel(SetupArgs S) {
  const int tid = threadIdx.x;
  int b = blockIdx.x;
  if (b < S.nbConv) {
    int i = b * 256 + tid;
    const float* x;
    unsigned short* xb;
    if (i < S.n4u) { x = S.xu; xb = S.xbu; }
    else { i -= S.n4u; if (i >= S.n4i) return; x = S.xi; xb = S.xbi; }
    float4 v = ((const float4*)x)[i];
    ushort4 o;
    o.x = f2bf(v.x); o.y = f2bf(v.y); o.z = f2bf(v.z); o.w = f2bf(v.w);
    ((ushort4*)xb)[i] = o;
    return;
  }
  b -= S.nbConv;
  if (b < S.nbHist) {
    int rel = 0;
    while (b >= S.nbh[rel]) { b -= S.nbh[rel]; rel++; }
    __shared__ int lh[NBB];
    for (int t = tid; t < NBB; t += 256) lh[t] = 0;
    __syncthreads();
    const int ne = S.ne[rel];
    const int* dsts = S.ei[rel] + ne;
    const int base = b * 2048;
#pragma unroll
    for (int k = 0; k < 8; k++) {
      int i = base + k * 256 + tid;
      if (i < ne) atomicAdd(&lh[dsts[i] >> 6], 1);
    }
    __syncthreads();
    for (int t = tid; t < NBB; t += 256)
      if (lh[t]) atomicAdd(&S.bh[rel * NBB + t], lh[t]);
    return;
  }
  b -= S.nbHist;
  // prep: 192 blocks x 256 thr covering 128*384 elements
  int idx = b * 256 + tid;
  if (idx >= 128 * 384) return;
  int n = idx / 384, k = idx - n * 384;
  float v;
  if (k < 128)      v = 0.5f * S.Wl_rev[n * 128 + k];
  else if (k < 256) v = 0.5f * S.Wl_fol[n * 128 + (k - 128)];
  else              v = 0.5f * (S.Wr_rev[n * 128 + (k - 256)] + S.Wr_fol[n * 128 + (k - 256)]);
  S.Wb_user[n * 384 + k] = f2bf(v);
  if (k < 256) {
    float w = (k < 128) ? S.Wl_rates[n * 128 + k] : S.Wr_rates[n * 128 + (k - 128)];
    S.Wb_item[n * 256 + k] = f2bf(w);
  }
  if (idx < 128) {
    S.b_item[idx] = S.bl_rates[idx];
    S.b_user[idx] = 0.5f * (S.bl_rev[idx] + S.bl_fol[idx]);
  }
}

// ---------------- exclusive scan of bucket hist (3 waves, 1 block) --------
__global__ void __launch_bounds__(192) scanb_kernel(const int* __restrict__ bh,
                                                    int* __restrict__ bbase,
                                                    int* __restrict__ bcur, int nbkt) {
  int w = threadIdx.x >> 6, l = threadIdx.x & 63;
  if (w >= 3) return;
  const int off = w * NBB;
  int v[13];
  int s0 = 0;
#pragma unroll
  for (int k = 0; k < 13; k++) {
    int idx = l * 13 + k;
    v[k] = (idx < nbkt) ? bh[off + idx] : 0;
    s0 += v[k];
  }
  int s = s0;
  for (int dlt = 1; dlt < 64; dlt <<= 1) {
    int t = __shfl_up(s, dlt);
    if (l >= dlt) s += t;
  }
  int run = s - s0;
#pragma unroll
  for (int k = 0; k < 13; k++) {
    int idx = l * 13 + k;
    if (idx < nbkt) { bbase[off + idx] = run; bcur[off + idx] = run; run += v[k]; }
  }
  if (l == 63) bbase[off + nbkt] = run;
}

// --------- bucket partition: packed (src | (dst&63)<<25), coalesced ------
struct PArgs { const int* ei[3]; int ne[3]; int nb[3]; unsigned* part[3]; };

__global__ void __launch_bounds__(256) part_kernel(PArgs P, int* __restrict__ bcur,
                                                   int nbkt) {
  int b = blockIdx.x, rel = 0;
  while (b >= P.nb[rel]) { b -= P.nb[rel]; rel++; }
  const int ne = P.ne[rel];
  const int* src = P.ei[rel];
  const int* dst = src + ne;
  const int base = b * 2048;
  const int tn = min(2048, ne - base);
  __shared__ int lh[NBB], lscan[NBB], gb[NBB], lcur[NBB];
  __shared__ uint2 pairs[2048];
  const int tid = threadIdx.x;
  for (int t = tid; t < NBB; t += 256) lh[t] = 0;
  __syncthreads();
#pragma unroll
  for (int k = 0; k < 8; k++) {
    int i = base + k * 256 + tid;
    if (i < ne) atomicAdd(&lh[dst[i] >> 6], 1);
  }
  __syncthreads();
  if (tid < 64) {
    int v[13];
    int s0 = 0;
#pragma unroll
    for (int k = 0; k < 13; k++) {
      int idx = tid * 13 + k;
      v[k] = (idx < NBB) ? lh[idx] : 0;
      s0 += v[k];
    }
    int s = s0;
    for (int dlt = 1; dlt < 64; dlt <<= 1) {
      int t = __shfl_up(s, dlt);
      if (tid >= dlt) s += t;
    }
    int run = s - s0;
#pragma unroll
    for (int k = 0; k < 13; k++) {
      int idx = tid * 13 + k;
      if (idx < NBB) { lscan[idx] = run; run += v[k]; }
    }
  }
  __syncthreads();
  for (int t = tid; t < nbkt; t += 256) {
    int c = lh[t];
    gb[t] = c ? atomicAdd(&bcur[rel * NBB + t], c) : 0;
    lcur[t] = lscan[t];
  }
  __syncthreads();
#pragma unroll
  for (int k = 0; k < 8; k++) {
    int i = base + k * 256 + tid;
    if (i < ne) {
      int d = dst[i];
      int slot = atomicAdd(&lcur[d >> 6], 1);
      pairs[slot] = (uint2){(unsigned)src[i], (unsigned)d};
    }
  }
  __syncthreads();
  unsigned* __restrict__ out = P.part[rel];
#pragma unroll
  for (int k = 0; k < 8; k++) {
    int slot = k * 256 + tid;
    if (slot < tn) {
      uint2 p = pairs[slot];
      int bin = (int)(p.y >> 6);
      out[gb[bin] + (slot - lscan[bin])] = p.x | ((p.y & 63u) << 25);
    }
  }
}

// ------ fused per-bucket sort + gather + mean (bf16 out), dual-row MLP ----
struct BAArgs {
  const unsigned* part[3];
  const unsigned short* xb[3];
  unsigned short* mean[3];
  int m[3];
};

__global__ void __launch_bounds__(256) bagg_kernel(BAArgs A, const int* __restrict__ bbase,
                                                   int nbkt) {
  const int rel = blockIdx.x / nbkt;
  const int b = blockIdx.x - rel * nbkt;
  const int bs = bbase[rel * NBB + b];
  const int be = bbase[rel * NBB + b + 1];
  const int n = be - bs;
  const unsigned* __restrict__ pp = A.part[rel] + bs;
  const unsigned short* __restrict__ x = A.xb[rel];
  unsigned short* __restrict__ mean = A.mean[rel];
  const int m = A.m[rel];
  const int tid = threadIdx.x;
  const int w = tid >> 6, lane = tid & 63;
  const size_t loff = lane * 2;
  __shared__ unsigned sorted[2048];
  __shared__ int lcnt[64], lofs[64], lcur[64];

  if (n > 2048) {   // fallback (never hit with uniform data): full scan
    for (int r = w; r < 64; r += 4) {
      int gdst = b * 64 + r;
      if (gdst >= m) break;
      float a0 = 0.f, a1 = 0.f;
      int cnt = 0;
      for (int j = 0; j < n; j++) {
        unsigned p = pp[j];
        if ((int)(p >> 25) == r) {
          unsigned v = *(const unsigned*)(x + (size_t)(p & 0x1FFFFFFu) * D + loff);
          a0 += bf2f((unsigned short)(v & 0xFFFFu));
          a1 += bf2f((unsigned short)(v >> 16));
          cnt++;
        }
      }
      float inv = 1.0f / (float)max(cnt, 1);
      unsigned o = (unsigned)f2bf(a0 * inv) | ((unsigned)f2bf(a1 * inv) << 16);
      *(unsigned*)(mean + (size_t)gdst * D + loff) = o;
    }
    return;
  }

  if (tid < 64) lcnt[tid] = 0;
  __syncthreads();
  for (int i = tid; i < n; i += 256) atomicAdd(&lcnt[pp[i] >> 25], 1);
  __syncthreads();
  if (tid < 64) {
    int v = lcnt[tid];
    int s = v;
    for (int dlt = 1; dlt < 64; dlt <<= 1) {
      int t = __shfl_up(s, dlt);
      if (tid >= dlt) s += t;
    }
    lofs[tid] = s - v;
  }
  __syncthreads();
  if (tid < 64) lcur[tid] = lofs[tid];
  __syncthreads();
  for (int i = tid; i < n; i += 256) {
    unsigned p = pp[i];
    int slot = atomicAdd(&lcur[p >> 25], 1);
    sorted[slot] = p & 0x1FFFFFFu;
  }
  __syncthreads();

  // gather: wave w handles row pairs (r, r+4) for r = w, w+8, ... (8 loads in flight)
  for (int r = w; r < 64; r += 8) {
    const int rA = r, rB = r + 4;
    const int gA = b * 64 + rA, gB = b * 64 + rB;
    if (gA >= m) break;
    const bool doB = gB < m;
    int jA = lofs[rA];
    const int eA = lcur[rA];
    int jB = doB ? lofs[rB] : 0;
    const int eB = doB ? lcur[rB] : 0;
    float aA0=0,aA1=0,bA0=0,bA1=0,cA0=0,cA1=0,dA0=0,dA1=0;
    float aB0=0,aB1=0,bB0=0,bB1=0,cB0=0,cB1=0,dB0=0,dB1=0;
    // dual-row main loop: 8 independent loads
    while (jA + 4 <= eA && jB + 4 <= eB) {
      unsigned sA0 = sorted[jA], sA1 = sorted[jA+1], sA2 = sorted[jA+2], sA3 = sorted[jA+3];
      unsigned sB0 = sorted[jB], sB1 = sorted[jB+1], sB2 = sorted[jB+2], sB3 = sorted[jB+3];
      unsigned vA0 = *(const unsigned*)(x + (size_t)sA0 * D + loff);
      unsigned vA1 = *(const unsigned*)(x + (size_t)sA1 * D + loff);
      unsigned vA2 = *(const unsigned*)(x + (size_t)sA2 * D + loff);
      unsigned vA3 = *(const unsigned*)(x + (size_t)sA3 * D + loff);
      unsigned vB0 = *(const unsigned*)(x + (size_t)sB0 * D + loff);
      unsigned vB1 = *(const unsigned*)(x + (size_t)sB1 * D + loff);
      unsigned vB2 = *(const unsigned*)(x + (size_t)sB2 * D + loff);
      unsigned vB3 = *(const unsigned*)(x + (size_t)sB3 * D + loff);
      aA0 += bf2f((unsigned short)(vA0 & 0xFFFFu)); aA1 += bf2f((unsigned short)(vA0 >> 16));
      bA0 += bf2f((unsigned short)(vA1 & 0xFFFFu)); bA1 += bf2f((unsigned short)(vA1 >> 16));
      cA0 += bf2f((unsigned short)(vA2 & 0xFFFFu)); cA1 += bf2f((unsigned short)(vA2 >> 16));
      dA0 += bf2f((unsigned short)(vA3 & 0xFFFFu)); dA1 += bf2f((unsigned short)(vA3 >> 16));
      aB0 += bf2f((unsigned short)(vB0 & 0xFFFFu)); aB1 += bf2f((unsigned short)(vB0 >> 16));
      bB0 += bf2f((unsigned short)(vB1 & 0xFFFFu)); bB1 += bf2f((unsigned short)(vB1 >> 16));
      cB0 += bf2f((unsigned short)(vB2 & 0xFFFFu)); cB1 += bf2f((unsigned short)(vB2 >> 16));
      dB0 += bf2f((unsigned short)(vB3 & 0xFFFFu)); dB1 += bf2f((unsigned short)(vB3 >> 16));
      jA += 4; jB += 4;
    }
    // drain A
    for (; jA + 4 <= eA; jA += 4) {
      unsigned s0 = sorted[jA], s1 = sorted[jA+1], s2 = sorted[jA+2], s3 = sorted[jA+3];
      unsigned v0 = *(const unsigned*)(x + (size_t)s0 * D + loff);
      unsigned v1 = *(const unsigned*)(x + (size_t)s1 * D + loff);
      unsigned v2 = *(const unsigned*)(x + (size_t)s2 * D + loff);
      unsigned v3 = *(const unsigned*)(x + (size_t)s3 * D + loff);
      aA0 += bf2f((unsigned short)(v0 & 0xFFFFu)); aA1 += bf2f((unsigned short)(v0 >> 16));
      bA0 += bf2f((unsigned short)(v1 & 0xFFFFu)); bA1 += bf2f((unsigned short)(v1 >> 16));
      cA0 += bf2f((unsigned short)(v2 & 0xFFFFu)); cA1 += bf2f((unsigned short)(v2 >> 16));
      dA0 += bf2f((unsigned short)(v3 & 0xFFFFu)); dA1 += bf2f((unsigned short)(v3 >> 16));
    }
    for (; jA < eA; jA++) {
      unsigned s = sorted[jA];
      unsigned v = *(const unsigned*)(x + (size_t)s * D + loff);
      aA0 += bf2f((unsigned short)(v & 0xFFFFu)); aA1 += bf2f((unsigned short)(v >> 16));
    }
    // drain B
    for (; jB + 4 <= eB; jB += 4) {
      unsigned s0 = sorted[jB], s1 = sorted[jB+1], s2 = sorted[jB+2], s3 = sorted[jB+3];
      unsigned v0 = *(const unsigned*)(x + (size_t)s0 * D + loff);
      unsigned v1 = *(const unsigned*)(x + (size_t)s1 * D + loff);
      unsigned v2 = *(const unsigned*)(x + (size_t)s2 * D + loff);
      unsigned v3 = *(const unsigned*)(x + (size_t)s3 * D + loff);
      aB0 += bf2f((unsigned short)(v0 & 0xFFFFu)); aB1 += bf2f((unsigned short)(v0 >> 16));
      bB0 += bf2f((unsigned short)(v1 & 0xFFFFu)); bB1 += bf2f((unsigned short)(v1 >> 16));
      cB0 += bf2f((unsigned short)(v2 & 0xFFFFu)); cB1 += bf2f((unsigned short)(v2 >> 16));
      dB0 += bf2f((unsigned short)(v3 & 0xFFFFu)); dB1 += bf2f((unsigned short)(v3 >> 16));
    }
    for (; jB < eB; jB++) {
      unsigned s = sorted[jB];
      unsigned v = *(const unsigned*)(x + (size_t)s * D + loff);
      aB0 += bf2f((unsigned short)(v & 0xFFFFu)); aB1 += bf2f((unsigned short)(v >> 16));
    }
    // write A
    {
      float v0 = (aA0 + bA0) + (cA0 + dA0);
      float v1 = (aA1 + bA1) + (cA1 + dA1);
      float inv = 1.0f / (float)max(eA - lofs[rA], 1);
      unsigned o = (unsigned)f2bf(v0 * inv) | ((unsigned)f2bf(v1 * inv) << 16);
      *(unsigned*)(mean + (size_t)gA * D + loff) = o;
    }
    if (doB) {
      float v0 = (aB0 + bB0) + (cB0 + dB0);
      float v1 = (aB1 + bB1) + (cB1 + dB1);
      float inv = 1.0f / (float)max(eB - lofs[rB], 1);
      unsigned o = (unsigned)f2bf(v0 * inv) | ((unsigned)f2bf(v1 * inv) << 16);
      *(unsigned*)(mean + (size_t)gB * D + loff) = o;
    }
  }
}

// -------- bf16 MFMA GEMM, 128x128 tile, both outputs in one launch --------
struct BSrcs { const unsigned short* s[3]; };
struct GemmArgs {
  BSrcs su, si;
  const unsigned short* wbU; const unsigned short* wbI;
  const float* bU; const float* bI;
  float* outU; float* outI;
  int MU, MI, nbU;
};

__global__ void __launch_bounds__(256) gemm2_kernel(GemmArgs A) {
  const bool isU = (int)blockIdx.x < A.nbU;
  const int bid = isU ? blockIdx.x : blockIdx.x - A.nbU;
  const BSrcs S = isU ? A.su : A.si;
  const unsigned short* __restrict__ Wb = isU ? A.wbU : A.wbI;
  const int K = isU ? 384 : 256;
  const float* __restrict__ bias = isU ? A.bU : A.bI;
  float* __restrict__ out = isU ? A.outU : A.outI;
  const int M = isU ? A.MU : A.MI;

  __shared__ __align__(16) unsigned short As[128][72];
  __shared__ __align__(16) unsigned short Ws[128][72];
  const int tid = threadIdx.x;
  const int lane = tid & 63;
  const int wave = tid >> 6;
  const int wr = (wave >> 1) * 64;   // wave row base
  const int wc = (wave & 1) * 64;    // wave col base
  const int l15 = lane & 15;
  const int quad = lane >> 4;
  const int m0 = bid * 128;

  f32x4 acc[4][4];
#pragma unroll
  for (int r = 0; r < 4; r++)
#pragma unroll
    for (int c = 0; c < 4; c++) acc[r][c] = (f32x4){0.f, 0.f, 0.f, 0.f};

  const int srow = tid >> 1, shalf = tid & 1;   // staging: 128 rows x 2 halves (32 shorts each)
  const int nchunks = K >> 6;
  for (int ch = 0; ch < nchunks; ch++) {
    const unsigned short* sp = S.s[ch >> 1];
    const int coff = (ch & 1) << 6;
    {
      int mm = min(m0 + srow, M - 1);   // clamp: dup rows harmless, outputs guarded
      const uint4* g = (const uint4*)(sp + (size_t)mm * D + coff + shalf * 32);
      uint4* ld = (uint4*)(&As[srow][shalf * 32]);
      ld[0] = g[0]; ld[1] = g[1]; ld[2] = g[2]; ld[3] = g[3];
    }
    {
      const uint4* g = (const uint4*)(Wb + (size_t)srow * K + ch * 64 + shalf * 32);
      uint4* ld = (uint4*)(&Ws[srow][shalf * 32]);
      ld[0] = g[0]; ld[1] = g[1]; ld[2] = g[2]; ld[3] = g[3];
    }
    __syncthreads();
#pragma unroll
    for (int kk = 0; kk < 64; kk += 32) {
      const int kb = kk + quad * 8;
      bf16x8 a0 = *(const bf16x8*)&As[wr + l15][kb];
      bf16x8 a1 = *(const bf16x8*)&As[wr + 16 + l15][kb];
      bf16x8 a2 = *(const bf16x8*)&As[wr + 32 + l15][kb];
      bf16x8 a3 = *(const bf16x8*)&As[wr + 48 + l15][kb];
      bf16x8 b0 = *(const bf16x8*)&Ws[wc + l15][kb];
      bf16x8 b1 = *(const bf16x8*)&Ws[wc + 16 + l15][kb];
      bf16x8 b2 = *(const bf16x8*)&Ws[wc + 32 + l15][kb];
      bf16x8 b3 = *(const bf16x8*)&Ws[wc + 48 + l15][kb];
      acc[0][0] = __builtin_amdgcn_mfma_f32_16x16x32_bf16(a0, b0, acc[0][0], 0, 0, 0);
      acc[0][1] = __builtin_amdgcn_mfma_f32_16x16x32_bf16(a0, b1, acc[0][1], 0, 0, 0);
      acc[0][2] = __builtin_amdgcn_mfma_f32_16x16x32_bf16(a0, b2, acc[0][2], 0, 0, 0);
      acc[0][3] = __builtin_amdgcn_mfma_f32_16x16x32_bf16(a0, b3, acc[0][3], 0, 0, 0);
      acc[1][0] = __builtin_amdgcn_mfma_f32_16x16x32_bf16(a1, b0, acc[1][0], 0, 0, 0);
      acc[1][1] = __builtin_amdgcn_mfma_f32_16x16x32_bf16(a1, b1, acc[1][1], 0, 0, 0);
      acc[1][2] = __builtin_amdgcn_mfma_f32_16x16x32_bf16(a1, b2, acc[1][2], 0, 0, 0);
      acc[1][3] = __builtin_amdgcn_mfma_f32_16x16x32_bf16(a1, b3, acc[1][3], 0, 0, 0);
      acc[2][0] = __builtin_amdgcn_mfma_f32_16x16x32_bf16(a2, b0, acc[2][0], 0, 0, 0);
      acc[2][1] = __builtin_amdgcn_mfma_f32_16x16x32_bf16(a2, b1, acc[2][1], 0, 0, 0);
      acc[2][2] = __builtin_amdgcn_mfma_f32_16x16x32_bf16(a2, b2, acc[2][2], 0, 0, 0);
      acc[2][3] = __builtin_amdgcn_mfma_f32_16x16x32_bf16(a2, b3, acc[2][3], 0, 0, 0);
      acc[3][0] = __builtin_amdgcn_mfma_f32_16x16x32_bf16(a3, b0, acc[3][0], 0, 0, 0);
      acc[3][1] = __builtin_amdgcn_mfma_f32_16x16x32_bf16(a3, b1, acc[3][1], 0, 0, 0);
      acc[3][2] = __builtin_amdgcn_mfma_f32_16x16x32_bf16(a3, b2, acc[3][2], 0, 0, 0);
      acc[3][3] = __builtin_amdgcn_mfma_f32_16x16x32_bf16(a3, b3, acc[3][3], 0, 0, 0);
    }
    __syncthreads();
  }
#pragma unroll
  for (int c = 0; c < 4; c++) {
    const int n = wc + c * 16 + l15;
    const float bv = bias[n];
#pragma unroll
    for (int r = 0; r < 4; r++) {
      const int mrow = m0 + wr + r * 16 + quad * 4;
#pragma unroll
      for (int i = 0; i < 4; i++) {
        if (mrow + i < M) out[(size_t)(mrow + i) * D + n] = acc[r][c][i] + bv;
      }
    }
  }
}

extern "C" void kernel_launch(void* const* d_in, const int* in_sizes, int n_in,
                              void* d_out, int out_size, void* d_ws, size_t ws_size,
                              hipStream_t stream) {
  const float* x_user   = (const float*)d_in[0];
  const float* x_item   = (const float*)d_in[1];
  const int*   ei_rates = (const int*)d_in[2];
  const int*   ei_rev   = (const int*)d_in[3];
  const int*   ei_fol   = (const int*)d_in[4];
  const float* Wl_rates = (const float*)d_in[5];
  const float* bl_rates = (const float*)d_in[6];
  const float* Wr_rates = (const float*)d_in[7];
  const float* Wl_rev   = (const float*)d_in[8];
  const float* bl_rev   = (const float*)d_in[9];
  const float* Wr_rev   = (const float*)d_in[10];
  const float* Wl_fol   = (const float*)d_in[11];
  const float* bl_fol   = (const float*)d_in[12];
  const float* Wr_fol   = (const float*)d_in[13];

  const int NU = in_sizes[0] / D;       // 50000
  const int NI = in_sizes[1] / D;       // 50000
  const int E_rates = in_sizes[2] / 2;
  const int E_rev   = in_sizes[3] / 2;
  const int E_fol   = in_sizes[4] / 2;
  const int nbkt = ((NU > NI ? NU : NI) + 63) / 64;   // 782

  // ---- workspace carve-up (byte-based, 16B aligned) ----
  char* wsb = (char*)d_ws;
  size_t off = 0;
  auto take = [&](size_t bytes) {
    char* p = wsb + off;
    off += (bytes + 15) & ~(size_t)15;
    return p;
  };
  int* bhist = (int*)take(3 * NBB * 4);          // zeroed
  const size_t zero_bytes = off;
  int* bbase = (int*)take(3 * NBB * 4);
  int* bcur  = (int*)take(3 * NBB * 4);
  unsigned* part_rates = (unsigned*)take((size_t)E_rates * 4);
  unsigned* part_rev   = (unsigned*)take((size_t)E_rev * 4);
  unsigned* part_fol   = (unsigned*)take((size_t)E_fol * 4);
  unsigned short* xb_user    = (unsigned short*)take((size_t)NU * D * 2);
  unsigned short* xb_item    = (unsigned short*)take((size_t)NI * D * 2);
  unsigned short* mean_rates = (unsigned short*)take((size_t)NI * D * 2);
  unsigned short* mean_rev   = (unsigned short*)take((size_t)NU * D * 2);
  unsigned short* mean_fol   = (unsigned short*)take((size_t)NU * D * 2);
  unsigned short* Wb_user    = (unsigned short*)take(128 * 384 * 2);
  unsigned short* Wb_item    = (unsigned short*)take(128 * 256 * 2);
  float* b_user = (float*)take(128 * 4);
  float* b_item = (float*)take(128 * 4);

  hipMemsetAsync(d_ws, 0, zero_bytes, stream);

  SetupArgs SA;
  SA.xu = x_user; SA.xi = x_item; SA.xbu = xb_user; SA.xbi = xb_item;
  SA.n4u = NU * D / 4; SA.n4i = NI * D / 4;
  SA.nbConv = (SA.n4u + SA.n4i + 255) / 256;
  SA.ei[0] = ei_rates; SA.ne[0] = E_rates; SA.nbh[0] = (E_rates + 2047) / 2048;
  SA.ei[1] = ei_rev;   SA.ne[1] = E_rev;   SA.nbh[1] = (E_rev + 2047) / 2048;
  SA.ei[2] = ei_fol;   SA.ne[2] = E_fol;   SA.nbh[2] = (E_fol + 2047) / 2048;
  SA.nbHist = SA.nbh[0] + SA.nbh[1] + SA.nbh[2];
  SA.bh = bhist;
  SA.Wl_rates = Wl_rates; SA.Wr_rates = Wr_rates; SA.bl_rates = bl_rates;
  SA.Wl_rev = Wl_rev; SA.Wr_rev = Wr_rev; SA.bl_rev = bl_rev;
  SA.Wl_fol = Wl_fol; SA.Wr_fol = Wr_fol; SA.bl_fol = bl_fol;
  SA.Wb_user = Wb_user; SA.Wb_item = Wb_item;
  SA.b_user = b_user; SA.b_item = b_item;
  const int nbPrep = (128 * 384 + 255) / 256;   // 192
  setup_kernel<<<SA.nbConv + SA.nbHist + nbPrep, 256, 0, stream>>>(SA);

  scanb_kernel<<<1, 192, 0, stream>>>(bhist, bbase, bcur, nbkt);

  PArgs P;
  P.ei[0] = ei_rates; P.ne[0] = E_rates; P.nb[0] = (E_rates + 2047) / 2048; P.part[0] = part_rates;
  P.ei[1] = ei_rev;   P.ne[1] = E_rev;   P.nb[1] = (E_rev + 2047) / 2048;   P.part[1] = part_rev;
  P.ei[2] = ei_fol;   P.ne[2] = E_fol;   P.nb[2] = (E_fol + 2047) / 2048;   P.part[2] = part_fol;
  part_kernel<<<P.nb[0] + P.nb[1] + P.nb[2], 256, 0, stream>>>(P, bcur, nbkt);

  BAArgs BA;
  BA.part[0] = part_rates; BA.xb[0] = xb_user; BA.mean[0] = mean_rates; BA.m[0] = NI;
  BA.part[1] = part_rev;   BA.xb[1] = xb_item; BA.mean[1] = mean_rev;   BA.m[1] = NU;
  BA.part[2] = part_fol;   BA.xb[2] = xb_user; BA.mean[2] = mean_fol;   BA.m[2] = NU;
  bagg_kernel<<<3 * nbkt, 256, 0, stream>>>(BA, bbase, nbkt);

  GemmArgs gma;
  gma.su.s[0] = mean_rev;   gma.su.s[1] = mean_fol; gma.su.s[2] = xb_user;
  gma.si.s[0] = mean_rates; gma.si.s[1] = xb_item;  gma.si.s[2] = nullptr;
  gma.wbU = Wb_user; gma.wbI = Wb_item;
  gma.bU = b_user;   gma.bI = b_item;
  gma.outU = (float*)d_out;
  gma.outI = (float*)d_out + (size_t)NU * D;
  gma.MU = NU; gma.MI = NI;
  gma.nbU = (NU + 127) / 128;
  const int nbI = (NI + 127) / 128;
  gemm2_kernel<<<gma.nbU + nbI, 256, 0, stream>>>(gma);
}

// Round 2
// 317.115 us; speedup vs baseline: 1.0238x; 1.0238x over previous
//
#include <hip/hip_runtime.h>

#define D 128
#define NBB 392   // bucket array stride (>= nbkt+1), nbkt = ceil(50000/128) = 391

typedef __attribute__((ext_vector_type(8))) short bf16x8;
typedef __attribute__((ext_vector_type(4))) float f32x4;

__device__ inline unsigned short f2bf(float f) {
  unsigned u = __builtin_bit_cast(unsigned, f);
  unsigned r = u + 0x7FFFu + ((u >> 16) & 1u);
  return (unsigned short)(r >> 16);
}
__device__ inline float bf2f(unsigned short b) {
  unsigned u = ((unsigned)b) << 16;
  return __builtin_bit_cast(float, u);
}

// ------- fused setup: conv (fp32->bf16) | bucket hist | weight prep -------
struct SetupArgs {
  const float* xu; const float* xi;
  unsigned short* xbu; unsigned short* xbi;
  int n4u, n4i, nbConv;
  const int* ei[3]; int ne[3]; int nbh[3]; int nbHist;
  int* bh;
  const float* Wl_rates; const float* Wr_rates; const float* bl_rates;
  const float* Wl_rev;   const float* Wr_rev;   const float* bl_rev;
  const float* Wl_fol;   const float* Wr_fol;   const float* bl_fol;
  unsigned short* Wb_user; unsigned short* Wb_item;
  float* b_user; float* b_item;
};

__global__ void __launch_bounds__(256) setup_kernel(SetupArgs S) {
  const int tid = threadIdx.x;
  int b = blockIdx.x;
  if (b < S.nbConv) {
    int i = b * 256 + tid;
    const float* x;
    unsigned short* xb;
    if (i < S.n4u) { x = S.xu; xb = S.xbu; }
    else { i -= S.n4u; if (i >= S.n4i) return; x = S.xi; xb = S.xbi; }
    float4 v = ((const float4*)x)[i];
    ushort4 o;
    o.x = f2bf(v.x); o.y = f2bf(v.y); o.z = f2bf(v.z); o.w = f2bf(v.w);
    ((ushort4*)xb)[i] = o;
    return;
  }
  b -= S.nbConv;
  if (b < S.nbHist) {
    int rel = 0;
    while (b >= S.nbh[rel]) { b -= S.nbh[rel]; rel++; }
    __shared__ int lh[NBB];
    for (int t = tid; t < NBB; t += 256) lh[t] = 0;
    __syncthreads();
    const int ne = S.ne[rel];
    const int* dsts = S.ei[rel] + ne;
    const int base = b * 2048;
#pragma unroll
    for (int k = 0; k < 8; k++) {
      int i = base + k * 256 + tid;
      if (i < ne) atomicAdd(&lh[dsts[i] >> 7], 1);
    }
    __syncthreads();
    for (int t = tid; t < NBB; t += 256)
      if (lh[t]) atomicAdd(&S.bh[rel * NBB + t], lh[t]);
    return;
  }
  b -= S.nbHist;
  int idx = b * 256 + tid;
  if (idx >= 128 * 384) return;
  int n = idx / 384, k = idx - n * 384;
  float v;
  if (k < 128)      v = 0.5f * S.Wl_rev[n * 128 + k];
  else if (k < 256) v = 0.5f * S.Wl_fol[n * 128 + (k - 128)];
  else              v = 0.5f * (S.Wr_rev[n * 128 + (k - 256)] + S.Wr_fol[n * 128 + (k - 256)]);
  S.Wb_user[n * 384 + k] = f2bf(v);
  if (k < 256) {
    float w = (k < 128) ? S.Wl_rates[n * 128 + k] : S.Wr_rates[n * 128 + (k - 128)];
    S.Wb_item[n * 256 + k] = f2bf(w);
  }
  if (idx < 128) {
    S.b_item[idx] = S.bl_rates[idx];
    S.b_user[idx] = 0.5f * (S.bl_rev[idx] + S.bl_fol[idx]);
  }
}

// ---------------- exclusive scan of bucket hist (3 waves, 1 block) --------
__global__ void __launch_bounds__(192) scanb_kernel(const int* __restrict__ bh,
                                                    int* __restrict__ bbase,
                                                    int* __restrict__ bcur, int nbkt) {
  int w = threadIdx.x >> 6, l = threadIdx.x & 63;
  if (w >= 3) return;
  const int off = w * NBB;
  int v[7];
  int s0 = 0;
#pragma unroll
  for (int k = 0; k < 7; k++) {
    int idx = l * 7 + k;
    v[k] = (idx < nbkt) ? bh[off + idx] : 0;
    s0 += v[k];
  }
  int s = s0;
  for (int dlt = 1; dlt < 64; dlt <<= 1) {
    int t = __shfl_up(s, dlt);
    if (l >= dlt) s += t;
  }
  int run = s - s0;
#pragma unroll
  for (int k = 0; k < 7; k++) {
    int idx = l * 7 + k;
    if (idx < nbkt) { bbase[off + idx] = run; bcur[off + idx] = run; run += v[k]; }
  }
  if (l == 63) bbase[off + nbkt] = run;
}

// --------- bucket partition: packed (src | (dst&127)<<25), coalesced ------
struct PArgs { const int* ei[3]; int ne[3]; int nb[3]; unsigned* part[3]; };

__global__ void __launch_bounds__(256) part_kernel(PArgs P, int* __restrict__ bcur,
                                                   int nbkt) {
  int b = blockIdx.x, rel = 0;
  while (b >= P.nb[rel]) { b -= P.nb[rel]; rel++; }
  const int ne = P.ne[rel];
  const int* src = P.ei[rel];
  const int* dst = src + ne;
  const int base = b * 4096;
  const int tn = min(4096, ne - base);
  __shared__ int lh[NBB], lscan[NBB], gb[NBB], lcur[NBB];
  __shared__ uint2 pairs[4096];
  const int tid = threadIdx.x;
  for (int t = tid; t < NBB; t += 256) lh[t] = 0;
  __syncthreads();
#pragma unroll
  for (int k = 0; k < 16; k++) {
    int i = base + k * 256 + tid;
    if (i < ne) atomicAdd(&lh[dst[i] >> 7], 1);
  }
  __syncthreads();
  if (tid < 64) {
    int v[7];
    int s0 = 0;
#pragma unroll
    for (int k = 0; k < 7; k++) {
      int idx = tid * 7 + k;
      v[k] = (idx < NBB) ? lh[idx] : 0;
      s0 += v[k];
    }
    int s = s0;
    for (int dlt = 1; dlt < 64; dlt <<= 1) {
      int t = __shfl_up(s, dlt);
      if (tid >= dlt) s += t;
    }
    int run = s - s0;
#pragma unroll
    for (int k = 0; k < 7; k++) {
      int idx = tid * 7 + k;
      if (idx < NBB) { lscan[idx] = run; run += v[k]; }
    }
  }
  __syncthreads();
  for (int t = tid; t < nbkt; t += 256) {
    int c = lh[t];
    gb[t] = c ? atomicAdd(&bcur[rel * NBB + t], c) : 0;
    lcur[t] = lscan[t];
  }
  __syncthreads();
#pragma unroll
  for (int k = 0; k < 16; k++) {
    int i = base + k * 256 + tid;
    if (i < ne) {
      int d = dst[i];
      int slot = atomicAdd(&lcur[d >> 7], 1);
      pairs[slot] = (uint2){(unsigned)src[i], (unsigned)d};
    }
  }
  __syncthreads();
  unsigned* __restrict__ out = P.part[rel];
#pragma unroll
  for (int k = 0; k < 16; k++) {
    int slot = k * 256 + tid;
    if (slot < tn) {
      uint2 p = pairs[slot];
      int bin = (int)(p.y >> 7);
      out[gb[bin] + (slot - lscan[bin])] = p.x | ((p.y & 127u) << 25);
    }
  }
}

// ------ fused per-bucket sort + gather + mean (bf16 out), 8-wave block ----
struct BAArgs {
  const unsigned* part[3];
  const unsigned short* xb[3];
  unsigned short* mean[3];
  int m[3];
};

__global__ void __launch_bounds__(512) bagg_kernel(BAArgs A, const int* __restrict__ bbase,
                                                   int nbkt) {
  const int rel = blockIdx.x / nbkt;
  const int b = blockIdx.x - rel * nbkt;
  const int bs = bbase[rel * NBB + b];
  const int be = bbase[rel * NBB + b + 1];
  const int n = be - bs;
  const unsigned* __restrict__ pp = A.part[rel] + bs;
  const unsigned short* __restrict__ x = A.xb[rel];
  unsigned short* __restrict__ mean = A.mean[rel];
  const int m = A.m[rel];
  const int tid = threadIdx.x;
  const int w = tid >> 6, lane = tid & 63;
  const size_t loff = lane * 2;
  __shared__ unsigned sorted[4096];
  __shared__ int lcnt[128], lofs[128], lcur[128];

  if (n > 4096) {   // fallback (never hit with uniform data): full scan
    for (int r = w; r < 128; r += 8) {
      int gdst = b * 128 + r;
      if (gdst >= m) break;
      float a0 = 0.f, a1 = 0.f;
      int cnt = 0;
      for (int j = 0; j < n; j++) {
        unsigned p = pp[j];
        if ((int)(p >> 25) == r) {
          unsigned v = *(const unsigned*)(x + (size_t)(p & 0x1FFFFFFu) * D + loff);
          a0 += bf2f((unsigned short)(v & 0xFFFFu));
          a1 += bf2f((unsigned short)(v >> 16));
          cnt++;
        }
      }
      float inv = 1.0f / (float)max(cnt, 1);
      unsigned o = (unsigned)f2bf(a0 * inv) | ((unsigned)f2bf(a1 * inv) << 16);
      *(unsigned*)(mean + (size_t)gdst * D + loff) = o;
    }
    return;
  }

  if (tid < 128) lcnt[tid] = 0;
  __syncthreads();
  for (int i = tid; i < n; i += 512) atomicAdd(&lcnt[pp[i] >> 25], 1);
  __syncthreads();
  if (tid < 64) {
    int v0 = lcnt[2 * tid], v1 = lcnt[2 * tid + 1];
    int s0 = v0 + v1, s = s0;
    for (int dlt = 1; dlt < 64; dlt <<= 1) {
      int t = __shfl_up(s, dlt);
      if (tid >= dlt) s += t;
    }
    int ex = s - s0;
    lofs[2 * tid] = ex;
    lofs[2 * tid + 1] = ex + v0;
  }
  __syncthreads();
  if (tid < 128) lcur[tid] = lofs[tid];
  __syncthreads();
  for (int i = tid; i < n; i += 512) {
    unsigned p = pp[i];
    int slot = atomicAdd(&lcur[p >> 25], 1);
    sorted[slot] = p & 0x1FFFFFFu;
  }
  __syncthreads();

  // gather: wave w handles row pairs (r, r+8) for r = w, w+16, ...
  for (int r = w; r < 128; r += 16) {
    const int rA = r, rB = r + 8;
    const int gA = b * 128 + rA, gB = b * 128 + rB;
    if (gA >= m) break;
    const bool doB = gB < m;
    int jA = lofs[rA];
    const int eA = lcur[rA];
    int jB = doB ? lofs[rB] : 0;
    const int eB = doB ? lcur[rB] : 0;
    float aA0=0,aA1=0,bA0=0,bA1=0,cA0=0,cA1=0,dA0=0,dA1=0;
    float aB0=0,aB1=0,bB0=0,bB1=0,cB0=0,cB1=0,dB0=0,dB1=0;
    while (jA + 4 <= eA && jB + 4 <= eB) {
      unsigned sA0 = sorted[jA], sA1 = sorted[jA+1], sA2 = sorted[jA+2], sA3 = sorted[jA+3];
      unsigned sB0 = sorted[jB], sB1 = sorted[jB+1], sB2 = sorted[jB+2], sB3 = sorted[jB+3];
      unsigned vA0 = *(const unsigned*)(x + (size_t)sA0 * D + loff);
      unsigned vA1 = *(const unsigned*)(x + (size_t)sA1 * D + loff);
      unsigned vA2 = *(const unsigned*)(x + (size_t)sA2 * D + loff);
      unsigned vA3 = *(const unsigned*)(x + (size_t)sA3 * D + loff);
      unsigned vB0 = *(const unsigned*)(x + (size_t)sB0 * D + loff);
      unsigned vB1 = *(const unsigned*)(x + (size_t)sB1 * D + loff);
      unsigned vB2 = *(const unsigned*)(x + (size_t)sB2 * D + loff);
      unsigned vB3 = *(const unsigned*)(x + (size_t)sB3 * D + loff);
      aA0 += bf2f((unsigned short)(vA0 & 0xFFFFu)); aA1 += bf2f((unsigned short)(vA0 >> 16));
      bA0 += bf2f((unsigned short)(vA1 & 0xFFFFu)); bA1 += bf2f((unsigned short)(vA1 >> 16));
      cA0 += bf2f((unsigned short)(vA2 & 0xFFFFu)); cA1 += bf2f((unsigned short)(vA2 >> 16));
      dA0 += bf2f((unsigned short)(vA3 & 0xFFFFu)); dA1 += bf2f((unsigned short)(vA3 >> 16));
      aB0 += bf2f((unsigned short)(vB0 & 0xFFFFu)); aB1 += bf2f((unsigned short)(vB0 >> 16));
      bB0 += bf2f((unsigned short)(vB1 & 0xFFFFu)); bB1 += bf2f((unsigned short)(vB1 >> 16));
      cB0 += bf2f((unsigned short)(vB2 & 0xFFFFu)); cB1 += bf2f((unsigned short)(vB2 >> 16));
      dB0 += bf2f((unsigned short)(vB3 & 0xFFFFu)); dB1 += bf2f((unsigned short)(vB3 >> 16));
      jA += 4; jB += 4;
    }
    for (; jA + 4 <= eA; jA += 4) {
      unsigned s0 = sorted[jA], s1 = sorted[jA+1], s2 = sorted[jA+2], s3 = sorted[jA+3];
      unsigned v0 = *(const unsigned*)(x + (size_t)s0 * D + loff);
      unsigned v1 = *(const unsigned*)(x + (size_t)s1 * D + loff);
      unsigned v2 = *(const unsigned*)(x + (size_t)s2 * D + loff);
      unsigned v3 = *(const unsigned*)(x + (size_t)s3 * D + loff);
      aA0 += bf2f((unsigned short)(v0 & 0xFFFFu)); aA1 += bf2f((unsigned short)(v0 >> 16));
      bA0 += bf2f((unsigned short)(v1 & 0xFFFFu)); bA1 += bf2f((unsigned short)(v1 >> 16));
      cA0 += bf2f((unsigned short)(v2 & 0xFFFFu)); cA1 += bf2f((unsigned short)(v2 >> 16));
      dA0 += bf2f((unsigned short)(v3 & 0xFFFFu)); dA1 += bf2f((unsigned short)(v3 >> 16));
    }
    for (; jA < eA; jA++) {
      unsigned s = sorted[jA];
      unsigned v = *(const unsigned*)(x + (size_t)s * D + loff);
      aA0 += bf2f((unsigned short)(v & 0xFFFFu)); aA1 += bf2f((unsigned short)(v >> 16));
    }
    for (; jB + 4 <= eB; jB += 4) {
      unsigned s0 = sorted[jB], s1 = sorted[jB+1], s2 = sorted[jB+2], s3 = sorted[jB+3];
      unsigned v0 = *(const unsigned*)(x + (size_t)s0 * D + loff);
      unsigned v1 = *(const unsigned*)(x + (size_t)s1 * D + loff);
      unsigned v2 = *(const unsigned*)(x + (size_t)s2 * D + loff);
      unsigned v3 = *(const unsigned*)(x + (size_t)s3 * D + loff);
      aB0 += bf2f((unsigned short)(v0 & 0xFFFFu)); aB1 += bf2f((unsigned short)(v0 >> 16));
      bB0 += bf2f((unsigned short)(v1 & 0xFFFFu)); bB1 += bf2f((unsigned short)(v1 >> 16));
      cB0 += bf2f((unsigned short)(v2 & 0xFFFFu)); cB1 += bf2f((unsigned short)(v2 >> 16));
      dB0 += bf2f((unsigned short)(v3 & 0xFFFFu)); dB1 += bf2f((unsigned short)(v3 >> 16));
    }
    for (; jB < eB; jB++) {
      unsigned s = sorted[jB];
      unsigned v = *(const unsigned*)(x + (size_t)s * D + loff);
      aB0 += bf2f((unsigned short)(v & 0xFFFFu)); aB1 += bf2f((unsigned short)(v >> 16));
    }
    {
      float v0 = (aA0 + bA0) + (cA0 + dA0);
      float v1 = (aA1 + bA1) + (cA1 + dA1);
      float inv = 1.0f / (float)max(eA - lofs[rA], 1);
      unsigned o = (unsigned)f2bf(v0 * inv) | ((unsigned)f2bf(v1 * inv) << 16);
      *(unsigned*)(mean + (size_t)gA * D + loff) = o;
    }
    if (doB) {
      float v0 = (aB0 + bB0) + (cB0 + dB0);
      float v1 = (aB1 + bB1) + (cB1 + dB1);
      float inv = 1.0f / (float)max(eB - lofs[rB], 1);
      unsigned o = (unsigned)f2bf(v0 * inv) | ((unsigned)f2bf(v1 * inv) << 16);
      *(unsigned*)(mean + (size_t)gB * D + loff) = o;
    }
  }
}

// -------- bf16 MFMA GEMM, 128x128 tile, both outputs in one launch --------
struct BSrcs { const unsigned short* s[3]; };
struct GemmArgs {
  BSrcs su, si;
  const unsigned short* wbU; const unsigned short* wbI;
  const float* bU; const float* bI;
  float* outU; float* outI;
  int MU, MI, nbU;
};

__global__ void __launch_bounds__(256) gemm2_kernel(GemmArgs A) {
  const bool isU = (int)blockIdx.x < A.nbU;
  const int bid = isU ? blockIdx.x : blockIdx.x - A.nbU;
  const BSrcs S = isU ? A.su : A.si;
  const unsigned short* __restrict__ Wb = isU ? A.wbU : A.wbI;
  const int K = isU ? 384 : 256;
  const float* __restrict__ bias = isU ? A.bU : A.bI;
  float* __restrict__ out = isU ? A.outU : A.outI;
  const int M = isU ? A.MU : A.MI;

  __shared__ __align__(16) unsigned short As[128][72];
  __shared__ __align__(16) unsigned short Ws[128][72];
  const int tid = threadIdx.x;
  const int lane = tid & 63;
  const int wave = tid >> 6;
  const int wr = (wave >> 1) * 64;
  const int wc = (wave & 1) * 64;
  const int l15 = lane & 15;
  const int quad = lane >> 4;
  const int m0 = bid * 128;

  f32x4 acc[4][4];
#pragma unroll
  for (int r = 0; r < 4; r++)
#pragma unroll
    for (int c = 0; c < 4; c++) acc[r][c] = (f32x4){0.f, 0.f, 0.f, 0.f};

  const int srow = tid >> 1, shalf = tid & 1;
  const int nchunks = K >> 6;
  for (int ch = 0; ch < nchunks; ch++) {
    const unsigned short* sp = S.s[ch >> 1];
    const int coff = (ch & 1) << 6;
    {
      int mm = min(m0 + srow, M - 1);
      const uint4* g = (const uint4*)(sp + (size_t)mm * D + coff + shalf * 32);
      uint4* ld = (uint4*)(&As[srow][shalf * 32]);
      ld[0] = g[0]; ld[1] = g[1]; ld[2] = g[2]; ld[3] = g[3];
    }
    {
      const uint4* g = (const uint4*)(Wb + (size_t)srow * K + ch * 64 + shalf * 32);
      uint4* ld = (uint4*)(&Ws[srow][shalf * 32]);
      ld[0] = g[0]; ld[1] = g[1]; ld[2] = g[2]; ld[3] = g[3];
    }
    __syncthreads();
#pragma unroll
    for (int kk = 0; kk < 64; kk += 32) {
      const int kb = kk + quad * 8;
      bf16x8 a0 = *(const bf16x8*)&As[wr + l15][kb];
      bf16x8 a1 = *(const bf16x8*)&As[wr + 16 + l15][kb];
      bf16x8 a2 = *(const bf16x8*)&As[wr + 32 + l15][kb];
      bf16x8 a3 = *(const bf16x8*)&As[wr + 48 + l15][kb];
      bf16x8 b0 = *(const bf16x8*)&Ws[wc + l15][kb];
      bf16x8 b1 = *(const bf16x8*)&Ws[wc + 16 + l15][kb];
      bf16x8 b2 = *(const bf16x8*)&Ws[wc + 32 + l15][kb];
      bf16x8 b3 = *(const bf16x8*)&Ws[wc + 48 + l15][kb];
      acc[0][0] = __builtin_amdgcn_mfma_f32_16x16x32_bf16(a0, b0, acc[0][0], 0, 0, 0);
      acc[0][1] = __builtin_amdgcn_mfma_f32_16x16x32_bf16(a0, b1, acc[0][1], 0, 0, 0);
      acc[0][2] = __builtin_amdgcn_mfma_f32_16x16x32_bf16(a0, b2, acc[0][2], 0, 0, 0);
      acc[0][3] = __builtin_amdgcn_mfma_f32_16x16x32_bf16(a0, b3, acc[0][3], 0, 0, 0);
      acc[1][0] = __builtin_amdgcn_mfma_f32_16x16x32_bf16(a1, b0, acc[1][0], 0, 0, 0);
      acc[1][1] = __builtin_amdgcn_mfma_f32_16x16x32_bf16(a1, b1, acc[1][1], 0, 0, 0);
      acc[1][2] = __builtin_amdgcn_mfma_f32_16x16x32_bf16(a1, b2, acc[1][2], 0, 0, 0);
      acc[1][3] = __builtin_amdgcn_mfma_f32_16x16x32_bf16(a1, b3, acc[1][3], 0, 0, 0);
      acc[2][0] = __builtin_amdgcn_mfma_f32_16x16x32_bf16(a2, b0, acc[2][0], 0, 0, 0);
      acc[2][1] = __builtin_amdgcn_mfma_f32_16x16x32_bf16(a2, b1, acc[2][1], 0, 0, 0);
      acc[2][2] = __builtin_amdgcn_mfma_f32_16x16x32_bf16(a2, b2, acc[2][2], 0, 0, 0);
      acc[2][3] = __builtin_amdgcn_mfma_f32_16x16x32_bf16(a2, b3, acc[2][3], 0, 0, 0);
      acc[3][0] = __builtin_amdgcn_mfma_f32_16x16x32_bf16(a3, b0, acc[3][0], 0, 0, 0);
      acc[3][1] = __builtin_amdgcn_mfma_f32_16x16x32_bf16(a3, b1, acc[3][1], 0, 0, 0);
      acc[3][2] = __builtin_amdgcn_mfma_f32_16x16x32_bf16(a3, b2, acc[3][2], 0, 0, 0);
      acc[3][3] = __builtin_amdgcn_mfma_f32_16x16x32_bf16(a3, b3, acc[3][3], 0, 0, 0);
    }
    __syncthreads();
  }
#pragma unroll
  for (int c = 0; c < 4; c++) {
    const int n = wc + c * 16 + l15;
    const float bv = bias[n];
#pragma unroll
    for (int r = 0; r < 4; r++) {
      const int mrow = m0 + wr + r * 16 + quad * 4;
#pragma unroll
      for (int i = 0; i < 4; i++) {
        if (mrow + i < M) out[(size_t)(mrow + i) * D + n] = acc[r][c][i] + bv;
      }
    }
  }
}

extern "C" void kernel_launch(void* const* d_in, const int* in_sizes, int n_in,
                              void* d_out, int out_size, void* d_ws, size_t ws_size,
                              hipStream_t stream) {
  const float* x_user   = (const float*)d_in[0];
  const float* x_item   = (const float*)d_in[1];
  const int*   ei_rates = (const int*)d_in[2];
  const int*   ei_rev   = (const int*)d_in[3];
  const int*   ei_fol   = (const int*)d_in[4];
  const float* Wl_rates = (const float*)d_in[5];
  const float* bl_rates = (const float*)d_in[6];
  const float* Wr_rates = (const float*)d_in[7];
  const float* Wl_rev   = (const float*)d_in[8];
  const float* bl_rev   = (const float*)d_in[9];
  const float* Wr_rev   = (const float*)d_in[10];
  const float* Wl_fol   = (const float*)d_in[11];
  const float* bl_fol   = (const float*)d_in[12];
  const float* Wr_fol   = (const float*)d_in[13];

  const int NU = in_sizes[0] / D;
  const int NI = in_sizes[1] / D;
  const int E_rates = in_sizes[2] / 2;
  const int E_rev   = in_sizes[3] / 2;
  const int E_fol   = in_sizes[4] / 2;
  const int nbkt = ((NU > NI ? NU : NI) + 127) / 128;   // 391

  char* wsb = (char*)d_ws;
  size_t off = 0;
  auto take = [&](size_t bytes) {
    char* p = wsb + off;
    off += (bytes + 15) & ~(size_t)15;
    return p;
  };
  int* bhist = (int*)take(3 * NBB * 4);
  const size_t zero_bytes = off;
  int* bbase = (int*)take(3 * NBB * 4);
  int* bcur  = (int*)take(3 * NBB * 4);
  unsigned* part_rates = (unsigned*)take((size_t)E_rates * 4);
  unsigned* part_rev   = (unsigned*)take((size_t)E_rev * 4);
  unsigned* part_fol   = (unsigned*)take((size_t)E_fol * 4);
  unsigned short* xb_user    = (unsigned short*)take((size_t)NU * D * 2);
  unsigned short* xb_item    = (unsigned short*)take((size_t)NI * D * 2);
  unsigned short* mean_rates = (unsigned short*)take((size_t)NI * D * 2);
  unsigned short* mean_rev   = (unsigned short*)take((size_t)NU * D * 2);
  unsigned short* mean_fol   = (unsigned short*)take((size_t)NU * D * 2);
  unsigned short* Wb_user    = (unsigned short*)take(128 * 384 * 2);
  unsigned short* Wb_item    = (unsigned short*)take(128 * 256 * 2);
  float* b_user = (float*)take(128 * 4);
  float* b_item = (float*)take(128 * 4);

  hipMemsetAsync(d_ws, 0, zero_bytes, stream);

  SetupArgs SA;
  SA.xu = x_user; SA.xi = x_item; SA.xbu = xb_user; SA.xbi = xb_item;
  SA.n4u = NU * D / 4; SA.n4i = NI * D / 4;
  SA.nbConv = (SA.n4u + SA.n4i + 255) / 256;
  SA.ei[0] = ei_rates; SA.ne[0] = E_rates; SA.nbh[0] = (E_rates + 2047) / 2048;
  SA.ei[1] = ei_rev;   SA.ne[1] = E_rev;   SA.nbh[1] = (E_rev + 2047) / 2048;
  SA.ei[2] = ei_fol;   SA.ne[2] = E_fol;   SA.nbh[2] = (E_fol + 2047) / 2048;
  SA.nbHist = SA.nbh[0] + SA.nbh[1] + SA.nbh[2];
  SA.bh = bhist;
  SA.Wl_rates = Wl_rates; SA.Wr_rates = Wr_rates; SA.bl_rates = bl_rates;
  SA.Wl_rev = Wl_rev; SA.Wr_rev = Wr_rev; SA.bl_rev = bl_rev;
  SA.Wl_fol = Wl_fol; SA.Wr_fol = Wr_fol; SA.bl_fol = bl_fol;
  SA.Wb_user = Wb_user; SA.Wb_item = Wb_item;
  SA.b_user = b_user; SA.b_item = b_item;
  const int nbPrep = (128 * 384 + 255) / 256;
  setup_kernel<<<SA.nbConv + SA.nbHist + nbPrep, 256, 0, stream>>>(SA);

  scanb_kernel<<<1, 192, 0, stream>>>(bhist, bbase, bcur, nbkt);

  PArgs P;
  P.ei[0] = ei_rates; P.ne[0] = E_rates; P.nb[0] = (E_rates + 4095) / 4096; P.part[0] = part_rates;
  P.ei[1] = ei_rev;   P.ne[1] = E_rev;   P.nb[1] = (E_rev + 4095) / 4096;   P.part[1] = part_rev;
  P.ei[2] = ei_fol;   P.ne[2] = E_fol;   P.nb[2] = (E_fol + 4095) / 4096;   P.part[2] = part_fol;
  part_kernel<<<P.nb[0] + P.nb[1] + P.nb[2], 256, 0, stream>>>(P, bcur, nbkt);

  BAArgs BA;
  BA.part[0] = part_rates; BA.xb[0] = xb_user; BA.mean[0] = mean_rates; BA.m[0] = NI;
  BA.part[1] = part_rev;   BA.xb[1] = xb_item; BA.mean[1] = mean_rev;   BA.m[1] = NU;
  BA.part[2] = part_fol;   BA.xb[2] = xb_user; BA.mean[2] = mean_fol;   BA.m[2] = NU;
  bagg_kernel<<<3 * nbkt, 512, 0, stream>>>(BA, bbase, nbkt);

  GemmArgs gma;
  gma.su.s[0] = mean_rev;   gma.su.s[1] = mean_fol; gma.su.s[2] = xb_user;
  gma.si.s[0] = mean_rates; gma.si.s[1] = xb_item;  gma.si.s[2] = nullptr;
  gma.wbU = Wb_user; gma.wbI = Wb_item;
  gma.bU = b_user;   gma.bI = b_item;
  gma.outU = (float*)d_out;
  gma.outI = (float*)d_out + (size_t)NU * D;
  gma.MU = NU; gma.MI = NI;
  gma.nbU = (NU + 127) / 128;
  const int nbI = (NI + 127) / 128;
  gemm2_kernel<<<gma.nbU + nbI, 256, 0, stream>>>(gma);
}

// Round 3
// 308.028 us; speedup vs baseline: 1.0540x; 1.0295x over previous
//
#include <hip/hip_runtime.h>

#define D 128
#define NBB 392   // bucket array stride (>= nbkt+1), nbkt = ceil(50000/128) = 391

typedef __attribute__((ext_vector_type(8))) short bf16x8;
typedef __attribute__((ext_vector_type(4))) float f32x4;

__device__ inline unsigned short f2bf(float f) {
  unsigned u = __builtin_bit_cast(unsigned, f);
  unsigned r = u + 0x7FFFu + ((u >> 16) & 1u);
  return (unsigned short)(r >> 16);
}
__device__ inline float bf2f(unsigned short b) {
  unsigned u = ((unsigned)b) << 16;
  return __builtin_bit_cast(float, u);
}
__device__ inline void upadd(uint2 v, float4& a) {
  a.x += bf2f((unsigned short)(v.x & 0xFFFFu));
  a.y += bf2f((unsigned short)(v.x >> 16));
  a.z += bf2f((unsigned short)(v.y & 0xFFFFu));
  a.w += bf2f((unsigned short)(v.y >> 16));
}

// ------- fused setup: conv (fp32->bf16) | bucket hist | weight prep -------
struct SetupArgs {
  const float* xu; const float* xi;
  unsigned short* xbu; unsigned short* xbi;
  int n4u, n4i, nbConv;
  const int* ei[3]; int ne[3]; int nbh[3]; int nbHist;
  int* bh;
  const float* Wl_rates; const float* Wr_rates; const float* bl_rates;
  const float* Wl_rev;   const float* Wr_rev;   const float* bl_rev;
  const float* Wl_fol;   const float* Wr_fol;   const float* bl_fol;
  unsigned short* Wb_user; unsigned short* Wb_item;
  float* b_user; float* b_item;
};

__global__ void __launch_bounds__(256) setup_kernel(SetupArgs S) {
  const int tid = threadIdx.x;
  int b = blockIdx.x;
  if (b < S.nbConv) {
    int i = b * 256 + tid;
    const float* x;
    unsigned short* xb;
    if (i < S.n4u) { x = S.xu; xb = S.xbu; }
    else { i -= S.n4u; if (i >= S.n4i) return; x = S.xi; xb = S.xbi; }
    float4 v = ((const float4*)x)[i];
    ushort4 o;
    o.x = f2bf(v.x); o.y = f2bf(v.y); o.z = f2bf(v.z); o.w = f2bf(v.w);
    ((ushort4*)xb)[i] = o;
    return;
  }
  b -= S.nbConv;
  if (b < S.nbHist) {
    int rel = 0;
    while (b >= S.nbh[rel]) { b -= S.nbh[rel]; rel++; }
    __shared__ int lh[NBB];
    for (int t = tid; t < NBB; t += 256) lh[t] = 0;
    __syncthreads();
    const int ne = S.ne[rel];
    const int* dsts = S.ei[rel] + ne;
    const int base = b * 2048;
#pragma unroll
    for (int k = 0; k < 8; k++) {
      int i = base + k * 256 + tid;
      if (i < ne) atomicAdd(&lh[dsts[i] >> 7], 1);
    }
    __syncthreads();
    for (int t = tid; t < NBB; t += 256)
      if (lh[t]) atomicAdd(&S.bh[rel * NBB + t], lh[t]);
    return;
  }
  b -= S.nbHist;
  int idx = b * 256 + tid;
  if (idx >= 128 * 384) return;
  int n = idx / 384, k = idx - n * 384;
  float v;
  if (k < 128)      v = 0.5f * S.Wl_rev[n * 128 + k];
  else if (k < 256) v = 0.5f * S.Wl_fol[n * 128 + (k - 128)];
  else              v = 0.5f * (S.Wr_rev[n * 128 + (k - 256)] + S.Wr_fol[n * 128 + (k - 256)]);
  S.Wb_user[n * 384 + k] = f2bf(v);
  if (k < 256) {
    float w = (k < 128) ? S.Wl_rates[n * 128 + k] : S.Wr_rates[n * 128 + (k - 128)];
    S.Wb_item[n * 256 + k] = f2bf(w);
  }
  if (idx < 128) {
    S.b_item[idx] = S.bl_rates[idx];
    S.b_user[idx] = 0.5f * (S.bl_rev[idx] + S.bl_fol[idx]);
  }
}

// ---------------- exclusive scan of bucket hist (3 waves, 1 block) --------
__global__ void __launch_bounds__(192) scanb_kernel(const int* __restrict__ bh,
                                                    int* __restrict__ bbase,
                                                    int* __restrict__ bcur, int nbkt) {
  int w = threadIdx.x >> 6, l = threadIdx.x & 63;
  if (w >= 3) return;
  const int off = w * NBB;
  int v[7];
  int s0 = 0;
#pragma unroll
  for (int k = 0; k < 7; k++) {
    int idx = l * 7 + k;
    v[k] = (idx < nbkt) ? bh[off + idx] : 0;
    s0 += v[k];
  }
  int s = s0;
  for (int dlt = 1; dlt < 64; dlt <<= 1) {
    int t = __shfl_up(s, dlt);
    if (l >= dlt) s += t;
  }
  int run = s - s0;
#pragma unroll
  for (int k = 0; k < 7; k++) {
    int idx = l * 7 + k;
    if (idx < nbkt) { bbase[off + idx] = run; bcur[off + idx] = run; run += v[k]; }
  }
  if (l == 63) bbase[off + nbkt] = run;
}

// --------- bucket partition: packed (src | (dst&127)<<25), coalesced ------
struct PArgs { const int* ei[3]; int ne[3]; int nb[3]; unsigned* part[3]; };

__global__ void __launch_bounds__(256) part_kernel(PArgs P, int* __restrict__ bcur,
                                                   int nbkt) {
  int b = blockIdx.x, rel = 0;
  while (b >= P.nb[rel]) { b -= P.nb[rel]; rel++; }
  const int ne = P.ne[rel];
  const int* src = P.ei[rel];
  const int* dst = src + ne;
  const int base = b * 4096;
  const int tn = min(4096, ne - base);
  __shared__ int lh[NBB], lscan[NBB], gb[NBB], lcur[NBB];
  __shared__ uint2 pairs[4096];
  const int tid = threadIdx.x;
  for (int t = tid; t < NBB; t += 256) lh[t] = 0;
  __syncthreads();
#pragma unroll
  for (int k = 0; k < 16; k++) {
    int i = base + k * 256 + tid;
    if (i < ne) atomicAdd(&lh[dst[i] >> 7], 1);
  }
  __syncthreads();
  if (tid < 64) {
    int v[7];
    int s0 = 0;
#pragma unroll
    for (int k = 0; k < 7; k++) {
      int idx = tid * 7 + k;
      v[k] = (idx < NBB) ? lh[idx] : 0;
      s0 += v[k];
    }
    int s = s0;
    for (int dlt = 1; dlt < 64; dlt <<= 1) {
      int t = __shfl_up(s, dlt);
      if (tid >= dlt) s += t;
    }
    int run = s - s0;
#pragma unroll
    for (int k = 0; k < 7; k++) {
      int idx = tid * 7 + k;
      if (idx < NBB) { lscan[idx] = run; run += v[k]; }
    }
  }
  __syncthreads();
  for (int t = tid; t < nbkt; t += 256) {
    int c = lh[t];
    gb[t] = c ? atomicAdd(&bcur[rel * NBB + t], c) : 0;
    lcur[t] = lscan[t];
  }
  __syncthreads();
#pragma unroll
  for (int k = 0; k < 16; k++) {
    int i = base + k * 256 + tid;
    if (i < ne) {
      int d = dst[i];
      int slot = atomicAdd(&lcur[d >> 7], 1);
      pairs[slot] = (uint2){(unsigned)src[i], (unsigned)d};
    }
  }
  __syncthreads();
  unsigned* __restrict__ out = P.part[rel];
#pragma unroll
  for (int k = 0; k < 16; k++) {
    int slot = k * 256 + tid;
    if (slot < tn) {
      uint2 p = pairs[slot];
      int bin = (int)(p.y >> 7);
      out[gb[bin] + (slot - lscan[bin])] = p.x | ((p.y & 127u) << 25);
    }
  }
}

// ------ fused per-bucket sort + gather + mean (bf16 out) ------------------
// gather uses half-wave edge pairs: lanes 0-31 = even edge, 32-63 = odd edge,
// dwordx2 per lane -> 512 B / instruction, shfl_xor(32) combine per row.
struct BAArgs {
  const unsigned* part[3];
  const unsigned short* xb[3];
  unsigned short* mean[3];
  int m[3];
};

__global__ void __launch_bounds__(256) bagg_kernel(BAArgs A, const int* __restrict__ bbase,
                                                   int nbkt) {
  const int rel = blockIdx.x / nbkt;
  const int b = blockIdx.x - rel * nbkt;
  const int bs = bbase[rel * NBB + b];
  const int be = bbase[rel * NBB + b + 1];
  const int n = be - bs;
  const unsigned* __restrict__ pp = A.part[rel] + bs;
  const unsigned short* __restrict__ x = A.xb[rel];
  unsigned short* __restrict__ mean = A.mean[rel];
  const int m = A.m[rel];
  const int tid = threadIdx.x;
  const int w = tid >> 6, lane = tid & 63;
  const int h = lane >> 5, l32 = lane & 31;
  const size_t c8 = (size_t)l32 * 4;   // column offset in shorts (8 B per lane)
  __shared__ unsigned sorted[4096];
  __shared__ int lcnt[128], lofs[128], lcur[128];

  if (n > 4096) {   // fallback (never hit with uniform data): full scan
    const size_t loff = (size_t)lane * 2;
    for (int r = w; r < 128; r += 4) {
      int gdst = b * 128 + r;
      if (gdst >= m) break;
      float a0 = 0.f, a1 = 0.f;
      int cnt = 0;
      for (int j = 0; j < n; j++) {
        unsigned p = pp[j];
        if ((int)(p >> 25) == r) {
          unsigned v = *(const unsigned*)(x + (size_t)(p & 0x1FFFFFFu) * D + loff);
          a0 += bf2f((unsigned short)(v & 0xFFFFu));
          a1 += bf2f((unsigned short)(v >> 16));
          cnt++;
        }
      }
      float inv = 1.0f / (float)max(cnt, 1);
      unsigned o = (unsigned)f2bf(a0 * inv) | ((unsigned)f2bf(a1 * inv) << 16);
      *(unsigned*)(mean + (size_t)gdst * D + loff) = o;
    }
    return;
  }

  if (tid < 128) lcnt[tid] = 0;
  __syncthreads();
  for (int i = tid; i < n; i += 256) atomicAdd(&lcnt[pp[i] >> 25], 1);
  __syncthreads();
  if (tid < 64) {
    int v0 = lcnt[2 * tid], v1 = lcnt[2 * tid + 1];
    int s0 = v0 + v1, s = s0;
    for (int dlt = 1; dlt < 64; dlt <<= 1) {
      int t = __shfl_up(s, dlt);
      if (tid >= dlt) s += t;
    }
    int ex = s - s0;
    lofs[2 * tid] = ex;
    lofs[2 * tid + 1] = ex + v0;
  }
  __syncthreads();
  if (tid < 128) lcur[tid] = lofs[tid];
  __syncthreads();
  for (int i = tid; i < n; i += 256) {
    unsigned p = pp[i];
    int slot = atomicAdd(&lcur[p >> 25], 1);
    sorted[slot] = p & 0x1FFFFFFu;
  }
  __syncthreads();

  // gather: wave w handles row pairs (r, r+4) for r = w, w+8, ...
  // 8 dwordx2 loads in flight = 4 KB/wave; 16 edges consumed per main iter.
  for (int r = w; r < 128; r += 8) {
    const int rA = r, rB = r + 4;
    const int gA = b * 128 + rA, gB = b * 128 + rB;
    if (gA >= m) break;
    const bool doB = gB < m;
    int jA = lofs[rA];
    const int eA = lcur[rA];
    int jB = doB ? lofs[rB] : 0;
    const int eB = doB ? lcur[rB] : 0;
    float4 aA = {0,0,0,0}, bA = {0,0,0,0}, cA = {0,0,0,0}, dA = {0,0,0,0};
    float4 aB = {0,0,0,0}, bB = {0,0,0,0}, cB = {0,0,0,0}, dB = {0,0,0,0};
    while (jA + 8 <= eA && jB + 8 <= eB) {
      unsigned sA0 = sorted[jA + h],     sA1 = sorted[jA + 2 + h];
      unsigned sA2 = sorted[jA + 4 + h], sA3 = sorted[jA + 6 + h];
      unsigned sB0 = sorted[jB + h],     sB1 = sorted[jB + 2 + h];
      unsigned sB2 = sorted[jB + 4 + h], sB3 = sorted[jB + 6 + h];
      uint2 vA0 = *(const uint2*)(x + (size_t)sA0 * D + c8);
      uint2 vA1 = *(const uint2*)(x + (size_t)sA1 * D + c8);
      uint2 vA2 = *(const uint2*)(x + (size_t)sA2 * D + c8);
      uint2 vA3 = *(const uint2*)(x + (size_t)sA3 * D + c8);
      uint2 vB0 = *(const uint2*)(x + (size_t)sB0 * D + c8);
      uint2 vB1 = *(const uint2*)(x + (size_t)sB1 * D + c8);
      uint2 vB2 = *(const uint2*)(x + (size_t)sB2 * D + c8);
      uint2 vB3 = *(const uint2*)(x + (size_t)sB3 * D + c8);
      upadd(vA0, aA); upadd(vA1, bA); upadd(vA2, cA); upadd(vA3, dA);
      upadd(vB0, aB); upadd(vB1, bB); upadd(vB2, cB); upadd(vB3, dB);
      jA += 8; jB += 8;
    }
    // drain A
    for (; jA + 8 <= eA; jA += 8) {
      unsigned s0 = sorted[jA + h],     s1 = sorted[jA + 2 + h];
      unsigned s2 = sorted[jA + 4 + h], s3 = sorted[jA + 6 + h];
      uint2 v0 = *(const uint2*)(x + (size_t)s0 * D + c8);
      uint2 v1 = *(const uint2*)(x + (size_t)s1 * D + c8);
      uint2 v2 = *(const uint2*)(x + (size_t)s2 * D + c8);
      uint2 v3 = *(const uint2*)(x + (size_t)s3 * D + c8);
      upadd(v0, aA); upadd(v1, bA); upadd(v2, cA); upadd(v3, dA);
    }
    for (; jA + 2 <= eA; jA += 2) {
      unsigned s = sorted[jA + h];
      uint2 v = *(const uint2*)(x + (size_t)s * D + c8);
      upadd(v, aA);
    }
    if (jA < eA && h == 0) {
      unsigned s = sorted[jA];
      uint2 v = *(const uint2*)(x + (size_t)s * D + c8);
      upadd(v, aA);
    }
    // drain B
    for (; jB + 8 <= eB; jB += 8) {
      unsigned s0 = sorted[jB + h],     s1 = sorted[jB + 2 + h];
      unsigned s2 = sorted[jB + 4 + h], s3 = sorted[jB + 6 + h];
      uint2 v0 = *(const uint2*)(x + (size_t)s0 * D + c8);
      uint2 v1 = *(const uint2*)(x + (size_t)s1 * D + c8);
      uint2 v2 = *(const uint2*)(x + (size_t)s2 * D + c8);
      uint2 v3 = *(const uint2*)(x + (size_t)s3 * D + c8);
      upadd(v0, aB); upadd(v1, bB); upadd(v2, cB); upadd(v3, dB);
    }
    for (; jB + 2 <= eB; jB += 2) {
      unsigned s = sorted[jB + h];
      uint2 v = *(const uint2*)(x + (size_t)s * D + c8);
      upadd(v, aB);
    }
    if (jB < eB && h == 0) {
      unsigned s = sorted[jB];
      uint2 v = *(const uint2*)(x + (size_t)s * D + c8);
      upadd(v, aB);
    }
    // reduce + combine halves + write A
    {
      float t0 = (aA.x + bA.x) + (cA.x + dA.x);
      float t1 = (aA.y + bA.y) + (cA.y + dA.y);
      float t2 = (aA.z + bA.z) + (cA.z + dA.z);
      float t3 = (aA.w + bA.w) + (cA.w + dA.w);
      t0 += __shfl_xor(t0, 32);
      t1 += __shfl_xor(t1, 32);
      t2 += __shfl_xor(t2, 32);
      t3 += __shfl_xor(t3, 32);
      float inv = 1.0f / (float)max(eA - lofs[rA], 1);
      if (lane < 32) {
        uint2 o;
        o.x = (unsigned)f2bf(t0 * inv) | ((unsigned)f2bf(t1 * inv) << 16);
        o.y = (unsigned)f2bf(t2 * inv) | ((unsigned)f2bf(t3 * inv) << 16);
        *(uint2*)(mean + (size_t)gA * D + c8) = o;
      }
    }
    if (doB) {
      float t0 = (aB.x + bB.x) + (cB.x + dB.x);
      float t1 = (aB.y + bB.y) + (cB.y + dB.y);
      float t2 = (aB.z + bB.z) + (cB.z + dB.z);
      float t3 = (aB.w + bB.w) + (cB.w + dB.w);
      t0 += __shfl_xor(t0, 32);
      t1 += __shfl_xor(t1, 32);
      t2 += __shfl_xor(t2, 32);
      t3 += __shfl_xor(t3, 32);
      float inv = 1.0f / (float)max(eB - lofs[rB], 1);
      if (lane < 32) {
        uint2 o;
        o.x = (unsigned)f2bf(t0 * inv) | ((unsigned)f2bf(t1 * inv) << 16);
        o.y = (unsigned)f2bf(t2 * inv) | ((unsigned)f2bf(t3 * inv) << 16);
        *(uint2*)(mean + (size_t)gB * D + c8) = o;
      }
    }
  }
}

// -------- bf16 MFMA GEMM, 128x128 tile, both outputs in one launch --------
struct BSrcs { const unsigned short* s[3]; };
struct GemmArgs {
  BSrcs su, si;
  const unsigned short* wbU; const unsigned short* wbI;
  const float* bU; const float* bI;
  float* outU; float* outI;
  int MU, MI, nbU;
};

__global__ void __launch_bounds__(256) gemm2_kernel(GemmArgs A) {
  const bool isU = (int)blockIdx.x < A.nbU;
  const int bid = isU ? blockIdx.x : blockIdx.x - A.nbU;
  const BSrcs S = isU ? A.su : A.si;
  const unsigned short* __restrict__ Wb = isU ? A.wbU : A.wbI;
  const int K = isU ? 384 : 256;
  const float* __restrict__ bias = isU ? A.bU : A.bI;
  float* __restrict__ out = isU ? A.outU : A.outI;
  const int M = isU ? A.MU : A.MI;

  __shared__ __align__(16) unsigned short As[128][72];
  __shared__ __align__(16) unsigned short Ws[128][72];
  const int tid = threadIdx.x;
  const int lane = tid & 63;
  const int wave = tid >> 6;
  const int wr = (wave >> 1) * 64;
  const int wc = (wave & 1) * 64;
  const int l15 = lane & 15;
  const int quad = lane >> 4;
  const int m0 = bid * 128;

  f32x4 acc[4][4];
#pragma unroll
  for (int r = 0; r < 4; r++)
#pragma unroll
    for (int c = 0; c < 4; c++) acc[r][c] = (f32x4){0.f, 0.f, 0.f, 0.f};

  const int srow = tid >> 1, shalf = tid & 1;
  const int nchunks = K >> 6;
  for (int ch = 0; ch < nchunks; ch++) {
    const unsigned short* sp = S.s[ch >> 1];
    const int coff = (ch & 1) << 6;
    {
      int mm = min(m0 + srow, M - 1);
      const uint4* g = (const uint4*)(sp + (size_t)mm * D + coff + shalf * 32);
      uint4* ld = (uint4*)(&As[srow][shalf * 32]);
      ld[0] = g[0]; ld[1] = g[1]; ld[2] = g[2]; ld[3] = g[3];
    }
    {
      const uint4* g = (const uint4*)(Wb + (size_t)srow * K + ch * 64 + shalf * 32);
      uint4* ld = (uint4*)(&Ws[srow][shalf * 32]);
      ld[0] = g[0]; ld[1] = g[1]; ld[2] = g[2]; ld[3] = g[3];
    }
    __syncthreads();
#pragma unroll
    for (int kk = 0; kk < 64; kk += 32) {
      const int kb = kk + quad * 8;
      bf16x8 a0 = *(const bf16x8*)&As[wr + l15][kb];
      bf16x8 a1 = *(const bf16x8*)&As[wr + 16 + l15][kb];
      bf16x8 a2 = *(const bf16x8*)&As[wr + 32 + l15][kb];
      bf16x8 a3 = *(const bf16x8*)&As[wr + 48 + l15][kb];
      bf16x8 b0 = *(const bf16x8*)&Ws[wc + l15][kb];
      bf16x8 b1 = *(const bf16x8*)&Ws[wc + 16 + l15][kb];
      bf16x8 b2 = *(const bf16x8*)&Ws[wc + 32 + l15][kb];
      bf16x8 b3 = *(const bf16x8*)&Ws[wc + 48 + l15][kb];
      acc[0][0] = __builtin_amdgcn_mfma_f32_16x16x32_bf16(a0, b0, acc[0][0], 0, 0, 0);
      acc[0][1] = __builtin_amdgcn_mfma_f32_16x16x32_bf16(a0, b1, acc[0][1], 0, 0, 0);
      acc[0][2] = __builtin_amdgcn_mfma_f32_16x16x32_bf16(a0, b2, acc[0][2], 0, 0, 0);
      acc[0][3] = __builtin_amdgcn_mfma_f32_16x16x32_bf16(a0, b3, acc[0][3], 0, 0, 0);
      acc[1][0] = __builtin_amdgcn_mfma_f32_16x16x32_bf16(a1, b0, acc[1][0], 0, 0, 0);
      acc[1][1] = __builtin_amdgcn_mfma_f32_16x16x32_bf16(a1, b1, acc[1][1], 0, 0, 0);
      acc[1][2] = __builtin_amdgcn_mfma_f32_16x16x32_bf16(a1, b2, acc[1][2], 0, 0, 0);
      acc[1][3] = __builtin_amdgcn_mfma_f32_16x16x32_bf16(a1, b3, acc[1][3], 0, 0, 0);
      acc[2][0] = __builtin_amdgcn_mfma_f32_16x16x32_bf16(a2, b0, acc[2][0], 0, 0, 0);
      acc[2][1] = __builtin_amdgcn_mfma_f32_16x16x32_bf16(a2, b1, acc[2][1], 0, 0, 0);
      acc[2][2] = __builtin_amdgcn_mfma_f32_16x16x32_bf16(a2, b2, acc[2][2], 0, 0, 0);
      acc[2][3] = __builtin_amdgcn_mfma_f32_16x16x32_bf16(a2, b3, acc[2][3], 0, 0, 0);
      acc[3][0] = __builtin_amdgcn_mfma_f32_16x16x32_bf16(a3, b0, acc[3][0], 0, 0, 0);
      acc[3][1] = __builtin_amdgcn_mfma_f32_16x16x32_bf16(a3, b1, acc[3][1], 0, 0, 0);
      acc[3][2] = __builtin_amdgcn_mfma_f32_16x16x32_bf16(a3, b2, acc[3][2], 0, 0, 0);
      acc[3][3] = __builtin_amdgcn_mfma_f32_16x16x32_bf16(a3, b3, acc[3][3], 0, 0, 0);
    }
    __syncthreads();
  }
#pragma unroll
  for (int c = 0; c < 4; c++) {
    const int n = wc + c * 16 + l15;
    const float bv = bias[n];
#pragma unroll
    for (int r = 0; r < 4; r++) {
      const int mrow = m0 + wr + r * 16 + quad * 4;
#pragma unroll
      for (int i = 0; i < 4; i++) {
        if (mrow + i < M) out[(size_t)(mrow + i) * D + n] = acc[r][c][i] + bv;
      }
    }
  }
}

extern "C" void kernel_launch(void* const* d_in, const int* in_sizes, int n_in,
                              void* d_out, int out_size, void* d_ws, size_t ws_size,
                              hipStream_t stream) {
  const float* x_user   = (const float*)d_in[0];
  const float* x_item   = (const float*)d_in[1];
  const int*   ei_rates = (const int*)d_in[2];
  const int*   ei_rev   = (const int*)d_in[3];
  const int*   ei_fol   = (const int*)d_in[4];
  const float* Wl_rates = (const float*)d_in[5];
  const float* bl_rates = (const float*)d_in[6];
  const float* Wr_rates = (const float*)d_in[7];
  const float* Wl_rev   = (const float*)d_in[8];
  const float* bl_rev   = (const float*)d_in[9];
  const float* Wr_rev   = (const float*)d_in[10];
  const float* Wl_fol   = (const float*)d_in[11];
  const float* bl_fol   = (const float*)d_in[12];
  const float* Wr_fol   = (const float*)d_in[13];

  const int NU = in_sizes[0] / D;
  const int NI = in_sizes[1] / D;
  const int E_rates = in_sizes[2] / 2;
  const int E_rev   = in_sizes[3] / 2;
  const int E_fol   = in_sizes[4] / 2;
  const int nbkt = ((NU > NI ? NU : NI) + 127) / 128;   // 391

  char* wsb = (char*)d_ws;
  size_t off = 0;
  auto take = [&](size_t bytes) {
    char* p = wsb + off;
    off += (bytes + 15) & ~(size_t)15;
    return p;
  };
  int* bhist = (int*)take(3 * NBB * 4);
  const size_t zero_bytes = off;
  int* bbase = (int*)take(3 * NBB * 4);
  int* bcur  = (int*)take(3 * NBB * 4);
  unsigned* part_rates = (unsigned*)take((size_t)E_rates * 4);
  unsigned* part_rev   = (unsigned*)take((size_t)E_rev * 4);
  unsigned* part_fol   = (unsigned*)take((size_t)E_fol * 4);
  unsigned short* xb_user    = (unsigned short*)take((size_t)NU * D * 2);
  unsigned short* xb_item    = (unsigned short*)take((size_t)NI * D * 2);
  unsigned short* mean_rates = (unsigned short*)take((size_t)NI * D * 2);
  unsigned short* mean_rev   = (unsigned short*)take((size_t)NU * D * 2);
  unsigned short* mean_fol   = (unsigned short*)take((size_t)NU * D * 2);
  unsigned short* Wb_user    = (unsigned short*)take(128 * 384 * 2);
  unsigned short* Wb_item    = (unsigned short*)take(128 * 256 * 2);
  float* b_user = (float*)take(128 * 4);
  float* b_item = (float*)take(128 * 4);

  hipMemsetAsync(d_ws, 0, zero_bytes, stream);

  SetupArgs SA;
  SA.xu = x_user; SA.xi = x_item; SA.xbu = xb_user; SA.xbi = xb_item;
  SA.n4u = NU * D / 4; SA.n4i = NI * D / 4;
  SA.nbConv = (SA.n4u + SA.n4i + 255) / 256;
  SA.ei[0] = ei_rates; SA.ne[0] = E_rates; SA.nbh[0] = (E_rates + 2047) / 2048;
  SA.ei[1] = ei_rev;   SA.ne[1] = E_rev;   SA.nbh[1] = (E_rev + 2047) / 2048;
  SA.ei[2] = ei_fol;   SA.ne[2] = E_fol;   SA.nbh[2] = (E_fol + 2047) / 2048;
  SA.nbHist = SA.nbh[0] + SA.nbh[1] + SA.nbh[2];
  SA.bh = bhist;
  SA.Wl_rates = Wl_rates; SA.Wr_rates = Wr_rates; SA.bl_rates = bl_rates;
  SA.Wl_rev = Wl_rev; SA.Wr_rev = Wr_rev; SA.bl_rev = bl_rev;
  SA.Wl_fol = Wl_fol; SA.Wr_fol = Wr_fol; SA.bl_fol = bl_fol;
  SA.Wb_user = Wb_user; SA.Wb_item = Wb_item;
  SA.b_user = b_user; SA.b_item = b_item;
  const int nbPrep = (128 * 384 + 255) / 256;
  setup_kernel<<<SA.nbConv + SA.nbHist + nbPrep, 256, 0, stream>>>(SA);

  scanb_kernel<<<1, 192, 0, stream>>>(bhist, bbase, bcur, nbkt);

  PArgs P;
  P.ei[0] = ei_rates; P.ne[0] = E_rates; P.nb[0] = (E_rates + 4095) / 4096; P.part[0] = part_rates;
  P.ei[1] = ei_rev;   P.ne[1] = E_rev;   P.nb[1] = (E_rev + 4095) / 4096;   P.part[1] = part_rev;
  P.ei[2] = ei_fol;   P.ne[2] = E_fol;   P.nb[2] = (E_fol + 4095) / 4096;   P.part[2] = part_fol;
  part_kernel<<<P.nb[0] + P.nb[1] + P.nb[2], 256, 0, stream>>>(P, bcur, nbkt);

  BAArgs BA;
  BA.part[0] = part_rates; BA.xb[0] = xb_user; BA.mean[0] = mean_rates; BA.m[0] = NI;
  BA.part[1] = part_rev;   BA.xb[1] = xb_item; BA.mean[1] = mean_rev;   BA.m[1] = NU;
  BA.part[2] = part_fol;   BA.xb[2] = xb_user; BA.mean[2] = mean_fol;   BA.m[2] = NU;
  bagg_kernel<<<3 * nbkt, 256, 0, stream>>>(BA, bbase, nbkt);

  GemmArgs gma;
  gma.su.s[0] = mean_rev;   gma.su.s[1] = mean_fol; gma.su.s[2] = xb_user;
  gma.si.s[0] = mean_rates; gma.si.s[1] = xb_item;  gma.si.s[2] = nullptr;
  gma.wbU = Wb_user; gma.wbI = Wb_item;
  gma.bU = b_user;   gma.bI = b_item;
  gma.outU = (float*)d_out;
  gma.outI = (float*)d_out + (size_t)NU * D;
  gma.MU = NU; gma.MI = NI;
  gma.nbU = (NU + 127) / 128;
  const int nbI = (NI + 127) / 128;
  gemm2_kernel<<<gma.nbU + nbI, 256, 0, stream>>>(gma);
}